// Round 16
// baseline (37.840 us; speedup 1.0000x reference)
//
#include <hip/hip_runtime.h>
#include <hip/hip_bf16.h>

// VQ-VAE vector quantizer, MI355X — SINGLE dispatch (+4B memset node).
// [k_all] 256 blocks x 512thr (1/CU, 8 waves): block owns 128 hw rows of one b.
//   - stage emb fp32 -> fp8 LDS image (x512) + cn=||e||^2, per block (L2-hot),
//     overlapped with lat HBM loads; NO separate prep dispatch
//   - A-frags direct from lat (regs, cvt fp8); row-norms free
//   - phase B (R8/R15): wave owns 16 rows, sweeps 1024 codes from LDS
//   - in-wave butterfly, gather q=emb[k*] fp32 -> [B,D,H,W], loss atomicAdd
//     into a memset-zeroed cell of d_out

typedef __attribute__((ext_vector_type(4))) float f32x4;

#define LOSS_SCALE (1.25f / 4194304.0f)
#define NEG2_INV_LAMBDA (-2.0f / 512.0f)

static __device__ inline unsigned cvt4_fp8(float a, float b, float c, float d) {
    int v = __builtin_amdgcn_cvt_pk_fp8_f32(a, b, 0, false);
    v = __builtin_amdgcn_cvt_pk_fp8_f32(c, d, v, true);
    return (unsigned)v;
}

// LDS: E @0 (128K, swz) | C @131072 (4K) | win @135168 (512) | rs @135680 (32)
//      = 135712 B, 1 block/CU.
__global__ __launch_bounds__(512, 1) void k_all(const float* __restrict__ lat,
                                                const float* __restrict__ emb,
                                                float* __restrict__ outq,
                                                float* __restrict__ loss) {
    __shared__ __align__(16) char lds[135712];
    char*  ldsE = lds;                       // fp8 swz [1024][128]
    float* ldsC = (float*)(lds + 131072);    // [1024]
    int*   win  = (int*)  (lds + 135168);    // [128]
    float* rs   = (float*)(lds + 135680);    // [8]

    const int t = threadIdx.x, bm = blockIdx.x;     // 256 blocks
    const int lane = t & 63, w = t >> 6;            // 8 waves
    const int l15 = lane & 15, lg = lane >> 4;
    const int b = bm >> 3, hw0 = (bm & 7) << 7;     // 128 rows

    // ---- lat loads first (HBM, longest latency) ----
    const float* lp = lat + ((size_t)b << 17) + hw0 + (w << 4) + l15;
    float xv[4][8];
#pragma unroll
    for (int ks = 0; ks < 4; ++ks)
#pragma unroll
        for (int j = 0; j < 8; ++j)
            xv[ks][j] = lp[(size_t)(ks * 32 + lg * 8 + j) << 10];

    // ---- stage emb fp32 -> fp8 E image + cn (L2-served, overlaps lat) ----
    // granule g = t + j*512: row = g>>4 (code), p8 = g&15 (8-fp8 slot).
    // lanes l15=0..15 at step j share row -> 16-lane reduce gives ||e_row||^2.
    {
        const float4* eg4 = (const float4*)emb;
#pragma unroll 4
        for (int j = 0; j < 32; ++j) {
            int g = t + (j << 9);
            int row = g >> 4, p8 = g & 15;
            float4 a = eg4[g * 2], c = eg4[g * 2 + 1];
            float ps = a.x*a.x + a.y*a.y + a.z*a.z + a.w*a.w
                     + c.x*c.x + c.y*c.y + c.z*c.z + c.w*c.w;
#pragma unroll
            for (int mk = 1; mk < 16; mk <<= 1) ps += __shfl_xor(ps, mk);
            uint2 v;
            v.x = cvt4_fp8(512.f*a.x, 512.f*a.y, 512.f*a.z, 512.f*a.w);
            v.y = cvt4_fp8(512.f*c.x, 512.f*c.y, 512.f*c.z, 512.f*c.w);
            *(uint2*)(ldsE + row * 128 + ((p8 * 8) ^ ((row & 7) << 4))) = v;
            if (l15 == 0) ldsC[row] = ps;
        }
    }

    // ---- A-frags + row norms ----
    float rn = 0.f;
    long av[4];
#pragma unroll
    for (int ks = 0; ks < 4; ++ks) {
#pragma unroll
        for (int j = 0; j < 8; ++j) rn = fmaf(xv[ks][j], xv[ks][j], rn);
        unsigned lo = cvt4_fp8(xv[ks][0], xv[ks][1], xv[ks][2], xv[ks][3]);
        unsigned hi = cvt4_fp8(xv[ks][4], xv[ks][5], xv[ks][6], xv[ks][7]);
        av[ks] = (long)(((unsigned long long)hi << 32) | lo);
    }
    __syncthreads();                 // E + cn resident

    // ---- phase B: barrier-free sweep of all 1024 codes from LDS ----
    float run_s[4]; int run_i[4];
#pragma unroll
    for (int r = 0; r < 4; ++r) { run_s[r] = 3.0e38f; run_i[r] = 0; }

    for (int ct = 0; ct < 8; ++ct) {
        float cnv[8];
#pragma unroll
        for (int c = 0; c < 8; ++c) cnv[c] = ldsC[(ct << 7) + (c << 4) + l15];

        f32x4 acc[8];
#pragma unroll
        for (int c = 0; c < 8; ++c) acc[c] = (f32x4){0.f, 0.f, 0.f, 0.f};
#pragma unroll
        for (int ks = 0; ks < 4; ++ks) {
            long bv[8];
#pragma unroll
            for (int c = 0; c < 8; ++c) {
                int rr = (ct << 7) + (c << 4) + l15;
                bv[c] = *(const long*)(ldsE + rr * 128 +
                         ((ks * 32 + lg * 8) ^ ((rr & 7) << 4)));
            }
#pragma unroll
            for (int c = 0; c < 8; ++c)
                acc[c] = __builtin_amdgcn_mfma_f32_16x16x32_fp8_fp8(av[ks], bv[c], acc[c], 0, 0, 0);
        }
#pragma unroll
        for (int c = 0; c < 8; ++c) {
            int kg = (ct << 7) + (c << 4) + l15;
#pragma unroll
            for (int r = 0; r < 4; ++r) {
                float s = fmaf(NEG2_INV_LAMBDA, acc[c][r], cnv[c]);
                if (s < run_s[r]) { run_s[r] = s; run_i[r] = kg; }
            }
        }
    }

    // ---- in-wave merge: butterfly over 16 cols; win + loss partials ----
    float bs = 0.f;
#pragma unroll
    for (int r = 0; r < 4; ++r) {
        float s = run_s[r]; int bi = run_i[r];
#pragma unroll
        for (int mask = 1; mask < 16; mask <<= 1) {
            float os = __shfl_xor(s, mask);
            int   oi = __shfl_xor(bi, mask);
            if (os < s || (os == s && oi < bi)) { s = os; bi = oi; }
        }
        if (l15 == 0) {
            win[(w << 4) + (lg << 2) + r] = bi;    // C row = lg*4 + reg
            bs += s;
        }
    }
    {
        float v = ((l15 == 0) ? bs : 0.f) + rn;
#pragma unroll
        for (int m = 1; m < 64; m <<= 1) v += __shfl_xor(v, m);
        if (lane == 0) rs[w] = v;
    }
    __syncthreads();
    if (t == 0) {
        float v = rs[0] + rs[1] + rs[2] + rs[3] + rs[4] + rs[5] + rs[6] + rs[7];
        atomicAdd(loss, v * LOSS_SCALE);
    }

    // ---- gather q = emb[k*] fp32, store [B,D,H,W] coalesced ----
    {
        const int rowl = t & 127, dg = t >> 7;      // 4 dgrps x 32 d
        const int bi = win[rowl];
        const float4* eg = (const float4*)(emb + ((size_t)bi << 7) + (dg << 5));
        float* ob = outq + ((size_t)b << 17) + ((size_t)(dg << 5) << 10) + hw0 + rowl;
#pragma unroll
        for (int jj = 0; jj < 8; ++jj) {
            float4 v = eg[jj];
            ob[(size_t)(jj * 4 + 0) << 10] = v.x;
            ob[(size_t)(jj * 4 + 1) << 10] = v.y;
            ob[(size_t)(jj * 4 + 2) << 10] = v.z;
            ob[(size_t)(jj * 4 + 3) << 10] = v.w;
        }
    }
}

extern "C" void kernel_launch(void* const* d_in, const int* in_sizes, int n_in,
                              void* d_out, int out_size, void* d_ws, size_t ws_size,
                              hipStream_t stream) {
    const float* lat = (const float*)d_in[0];   // [32,128,32,32]
    const float* emb = (const float*)d_in[1];   // [1024,128]
    float* out = (float*)d_out;                 // q (4194304) + vq_loss (1)
    float* loss = out + 4194304;

    hipMemsetAsync(loss, 0, 4, stream);         // zero the loss accumulator
    k_all<<<256, 512, 0, stream>>>(lat, emb, out, loss);
}